// Round 5
// baseline (11422.804 us; speedup 1.0000x reference)
//
#include <hip/hip_runtime.h>
#include <hip/hip_bf16.h>

#define S_LEN 16384
#define N_IN 23
#define CH 128
#define NCHUNK (S_LEN / CH)

// ---------------- fast activations (v_exp_f32 + v_rcp_f32) ----------------
__device__ __forceinline__ float fsig(float x) {
    return __builtin_amdgcn_rcpf(1.f + __expf(-x));   // exp(+inf)->inf, rcp(inf)->0: safe
}
__device__ __forceinline__ float ftanh_fast(float x) {
    float e = __expf(-2.f * fabsf(x));                // in (0,1]
    float r = (1.f - e) * __builtin_amdgcn_rcpf(1.f + e);
    return x >= 0.f ? r : -r;
}

// ---------------- dtype autodetect (bf16 vs fp32 input buffers) ----------------
__global__ void detect_kernel(const void* probe, int nsamp, int* flag)
{
    if (blockIdx.x == 0 && threadIdx.x == 0) {
        const unsigned short* p = (const unsigned short*)probe;
        int isbf16 = 1;
        for (int i = 0; i < nsamp; i++) {
            float v = __uint_as_float(((unsigned int)p[i]) << 16);
            if (!(fabsf(v) < 1e4f)) { isbf16 = 0; break; }
        }
        *flag = isbf16;
    }
}

// ---------------- ingest: convert all inputs to fp32 in ws ----------------
struct IngestArgs {
    const void* src[N_IN];
    float*      dst[N_IN];
    int         n[N_IN];
};

__global__ void ingest_kernel(IngestArgs args, const int* __restrict__ flag)
{
    const int isbf16 = *flag;
    const int tid    = blockIdx.x * blockDim.x + threadIdx.x;
    const int stride = gridDim.x * blockDim.x;
    for (int i = 0; i < N_IN; i++) {
        const int n = args.n[i];
        float* dst  = args.dst[i];
        if (isbf16) {
            const unsigned short* s = (const unsigned short*)args.src[i];
            for (int j = tid; j < n; j += stride)
                dst[j] = __uint_as_float(((unsigned int)s[j]) << 16);
        } else {
            const float* s = (const float*)args.src[i];
            for (int j = tid; j < n; j += stride)
                dst[j] = s[j];
        }
    }
}

// ---------------- zero the progress flags (ws is poisoned each launch) --------
__global__ void init_kernel(int* prog)
{
    int t = threadIdx.x;
    if (t < 7 * 64) prog[t] = 0;
}

// ---------------- fc1 + fc2 (parallel) ----------------
__global__ void fc12_kernel(const float* __restrict__ x,
                            const float* __restrict__ W1, const float* __restrict__ b1,
                            const float* __restrict__ W2, const float* __restrict__ b2,
                            float* __restrict__ h2out)
{
    int s = blockIdx.x * blockDim.x + threadIdx.x;
    if (s >= S_LEN) return;
    float xin[6];
#pragma unroll
    for (int k = 0; k < 6; k++) xin[k] = x[s * 6 + k];
    float h1[20];
#pragma unroll
    for (int j = 0; j < 20; j++) {
        float a = b1[j];
#pragma unroll
        for (int k = 0; k < 6; k++) a += W1[j * 6 + k] * xin[k];
        h1[j] = a > 0.f ? a : 0.f;
    }
#pragma unroll
    for (int j = 0; j < 20; j++) {
        float a = b2[j];
#pragma unroll
        for (int k = 0; k < 20; k++) a += W2[j * 20 + k] * h1[k];
        h2out[s * 20 + j] = a > 0.f ? a : 0.f;
    }
}

// ---------------- pipelined LSTM layer (one block, 192 threads = 3 waves) -----
// Every thread t is one gate row (Wih row + Whh row in VGPRs).
// ONE barrier per step; parity-double-buffered gates; each wave redundantly
// computes the c/h update for cells j=lane<48 into its OWN private h copy
// (intra-wave DS ordering -> no second barrier). Wave 0 also records h_hist.
template <int DIN>
__device__ void lstm_block(const float* __restrict__ in,     // [S, DIN]
                           const float* __restrict__ Wih,    // [192, DIN]
                           const float* __restrict__ Whh,    // [192, 48]
                           const float* __restrict__ bih,
                           const float* __restrict__ bhh,
                           float* __restrict__ hseq,         // [S, 48]
                           int* my_prog, int* prev_prog, float* smem)
{
    const int t    = threadIdx.x;    // 0..191
    const int wv   = t >> 6;         // 0..2
    const int lane = t & 63;

    float* x_chunk = smem;                         // CH*DIN
    float* h_hist  = x_chunk + CH * DIN;           // CH*48
    float* gates2  = h_hist + CH * 48;             // 2*192
    float* h_priv  = gates2 + 2 * 192;             // 3*64 (64-float aligned regions)

    float wih[DIN];
    float whh[48];
#pragma unroll
    for (int k = 0; k < DIN; k++) wih[k] = Wih[t * DIN + k];
#pragma unroll
    for (int k = 0; k < 48; k++) whh[k] = Whh[t * 48 + k];
    const float bsum = bih[t] + bhh[t];
    const bool tanh_gate = (t >= 96 && t < 144);

    float* h_mine = h_priv + wv * 64;
    if (lane < 48) h_mine[lane] = 0.f;
    float ccell = 0.f;
    __syncthreads();

    const float4* h4 = (const float4*)h_mine;

    for (int ch = 0; ch < NCHUNK; ch++) {
        if (prev_prog && t == 0) {
            while (__hip_atomic_load(prev_prog, __ATOMIC_ACQUIRE, __HIP_MEMORY_SCOPE_AGENT) < ch + 1)
                __builtin_amdgcn_s_sleep(2);
        }
        __syncthreads();
        // cooperative input-chunk load (global -> LDS), float4-coalesced
        {
            const float4* gsrc = (const float4*)(in + (size_t)ch * CH * DIN);
            float4* ldst = (float4*)x_chunk;
            for (int i = t; i < CH * DIN / 4; i += 192) ldst[i] = gsrc[i];
        }
        __syncthreads();

        for (int sl = 0; sl < CH; sl++) {
            float* g = gates2 + (sl & 1) * 192;
            // ---- phase A: all 192 threads compute their gate pre-activation ----
            {
                const float4* x4 = (const float4*)(x_chunk + sl * DIN);
                float a0 = 0.f, a1 = 0.f, a2 = 0.f, a3 = 0.f;
#pragma unroll
                for (int k = 0; k < 12; k++) {
                    float4 hv = h4[k];
                    a0 += whh[4 * k + 0] * hv.x;
                    a1 += whh[4 * k + 1] * hv.y;
                    a2 += whh[4 * k + 2] * hv.z;
                    a3 += whh[4 * k + 3] * hv.w;
                }
#pragma unroll
                for (int k = 0; k < DIN / 4; k++) {
                    float4 xv = x4[k];
                    a0 += wih[4 * k + 0] * xv.x;
                    a1 += wih[4 * k + 1] * xv.y;
                    a2 += wih[4 * k + 2] * xv.z;
                    a3 += wih[4 * k + 3] * xv.w;
                }
                float a = bsum + ((a0 + a1) + (a2 + a3));
                // i,f,o: sigmoid; g: tanh(a)=2*sigmoid(2a)-1 (NaN-safe)
                g[t] = tanh_gate ? (2.f * fsig(2.f * a) - 1.f) : fsig(a);
            }
            __syncthreads();   // the ONLY barrier in the step
            // ---- phase B: redundant c/h update in every wave (cells j=lane) ----
            if (lane < 48) {
                float iv = g[lane], fv = g[lane + 48], gv = g[lane + 96], ov = g[lane + 144];
                ccell = fv * ccell + iv * gv;
                float h = ov * ftanh_fast(ccell);
                h_mine[lane] = h;                       // own-wave copy, no barrier
                if (wv == 0) h_hist[sl * 48 + lane] = h;
            }
            // next step's gate writes go to the other parity buffer -> no WAR race
        }
        __syncthreads();   // h_hist complete; also drains before store

        // cooperative output-chunk store (LDS -> global)
        {
            const float4* lsrc = (const float4*)h_hist;
            float4* gdst = (float4*)(hseq + (size_t)ch * CH * 48);
            for (int i = t; i < CH * 12; i += 192) gdst[i] = lsrc[i];
        }
        __syncthreads();   // drains each wave's vmcnt before progress is posted
        if (t == 0)
            __hip_atomic_store(my_prog, ch + 1, __ATOMIC_RELEASE, __HIP_MEMORY_SCOPE_AGENT);
    }
}

// ---------------- pipelined tanh-RNN layer (one block, H=24) ------------------
// Step loop runs on wave 0 only (lanes 0..23), barrier-free (wave lockstep).
template <int DIN>
__device__ void rnn_block(const float* __restrict__ in,     // [S, DIN]
                          const float* __restrict__ Wih,    // [24, DIN]
                          const float* __restrict__ Whh,    // [24, 24]
                          const float* __restrict__ bih,
                          const float* __restrict__ bhh,
                          float* __restrict__ hseq,         // [S, 24]
                          int* my_prog, int* prev_prog, float* smem)
{
    const int t = threadIdx.x;
    float* x_chunk = smem;                        // CH*DIN
    float* h_hist  = smem + CH * DIN;             // CH*24
    float* h_sh    = h_hist + CH * 24;            // 24

    float wih[DIN];
    float whh[24];
    float bsum = 0.f;
    const bool gate_t = (t < 24);
    if (gate_t) {
#pragma unroll
        for (int k = 0; k < DIN; k++) wih[k] = Wih[t * DIN + k];
#pragma unroll
        for (int k = 0; k < 24; k++) whh[k] = Whh[t * 24 + k];
        bsum = bih[t] + bhh[t];
        h_sh[t] = 0.f;
    }
    const float4* h4 = (const float4*)h_sh;
    __syncthreads();

    for (int ch = 0; ch < NCHUNK; ch++) {
        if (prev_prog && t == 0) {
            while (__hip_atomic_load(prev_prog, __ATOMIC_ACQUIRE, __HIP_MEMORY_SCOPE_AGENT) < ch + 1)
                __builtin_amdgcn_s_sleep(2);
        }
        __syncthreads();
        {
            const float4* gsrc = (const float4*)(in + (size_t)ch * CH * DIN);
            float4* ldst = (float4*)x_chunk;
            for (int i = t; i < CH * DIN / 4; i += 192) ldst[i] = gsrc[i];
        }
        __syncthreads();

        if (t < 64) {
            for (int sl = 0; sl < CH; sl++) {
                if (gate_t) {
                    const float4* x4 = (const float4*)(x_chunk + sl * DIN);
                    float a0 = 0.f, a1 = 0.f, a2 = 0.f, a3 = 0.f;
#pragma unroll
                    for (int k = 0; k < 6; k++) {
                        float4 hv = h4[k];
                        a0 += whh[4 * k + 0] * hv.x;
                        a1 += whh[4 * k + 1] * hv.y;
                        a2 += whh[4 * k + 2] * hv.z;
                        a3 += whh[4 * k + 3] * hv.w;
                    }
#pragma unroll
                    for (int k = 0; k < DIN / 4; k++) {
                        float4 xv = x4[k];
                        a0 += wih[4 * k + 0] * xv.x;
                        a1 += wih[4 * k + 1] * xv.y;
                        a2 += wih[4 * k + 2] * xv.z;
                        a3 += wih[4 * k + 3] * xv.w;
                    }
                    float hnew = ftanh_fast(bsum + ((a0 + a1) + (a2 + a3)));
                    // wave-lockstep: all lanes' ds_reads of h_sh precede this write
                    h_sh[t] = hnew;
                    h_hist[sl * 24 + t] = hnew;
                }
            }
        }
        __syncthreads();

        {
            const float4* lsrc = (const float4*)h_hist;
            float4* gdst = (float4*)(hseq + (size_t)ch * CH * 24);
            for (int i = t; i < CH * 6; i += 192) gdst[i] = lsrc[i];
        }
        __syncthreads();
        if (t == 0)
            __hip_atomic_store(my_prog, ch + 1, __ATOMIC_RELEASE, __HIP_MEMORY_SCOPE_AGENT);
    }
}

// ---------------- the 7-layer pipeline megakernel ----------------
struct PipeArgs {
    const float* h2;
    const float* l0_Wih; const float* l0_Whh; const float* l0_bih; const float* l0_bhh;
    const float* lr_Wih; const float* lr_Whh; const float* lr_bih; const float* lr_bhh;
    const float* r0_Wih; const float* r0_Whh; const float* r0_bih; const float* r0_bhh;
    const float* r1_Wih; const float* r1_Whh; const float* r1_bih; const float* r1_bhh;
    float* seq0; float* seq1; float* seq2; float* seq3; float* seq4;
    float* rnnA; float* rnnB;
    int* prog;   // progress[l] at prog[l*64]
};

__global__ void __launch_bounds__(192, 1) pipeline_kernel(PipeArgs a)
{
    // one shared arena, partitioned per stage (worst case lstm<48>: 12,864 floats)
    __shared__ float smem[12864];
    const int b = blockIdx.x;
    float* seqs[5] = {a.seq0, a.seq1, a.seq2, a.seq3, a.seq4};
    if (b == 0) {
        lstm_block<20>(a.h2, a.l0_Wih, a.l0_Whh, a.l0_bih, a.l0_bhh,
                       a.seq0, a.prog + 0, nullptr, smem);
    } else if (b <= 4) {
        const int l = b - 1;
        lstm_block<48>(seqs[l],
                       a.lr_Wih + (size_t)l * 192 * 48,
                       a.lr_Whh + (size_t)l * 192 * 48,
                       a.lr_bih + (size_t)l * 192,
                       a.lr_bhh + (size_t)l * 192,
                       seqs[l + 1], a.prog + b * 64, a.prog + (b - 1) * 64, smem);
    } else if (b == 5) {
        rnn_block<48>(a.seq4, a.r0_Wih, a.r0_Whh, a.r0_bih, a.r0_bhh,
                      a.rnnA, a.prog + 5 * 64, a.prog + 4 * 64, smem);
    } else {
        rnn_block<24>(a.rnnA, a.r1_Wih, a.r1_Whh, a.r1_bih, a.r1_bhh,
                      a.rnnB, a.prog + 6 * 64, a.prog + 5 * 64, smem);
    }
}

// ---------------- epilogue: relu + fc4, bf16 or fp32 out per flag ----------------
__global__ void out_kernel(const float* __restrict__ hin,
                           const float* __restrict__ W,  // [2, 24]
                           const float* __restrict__ b,  // [2]
                           void* __restrict__ out,
                           const int* __restrict__ flag)
{
    int s = blockIdx.x * blockDim.x + threadIdx.x;
    if (s >= S_LEN) return;
    const int isbf16 = *flag;
    float h[24];
#pragma unroll
    for (int k = 0; k < 24; k++) {
        float v = hin[s * 24 + k];
        h[k] = v > 0.f ? v : 0.f;
    }
#pragma unroll
    for (int j = 0; j < 2; j++) {
        float a = b[j];
#pragma unroll
        for (int k = 0; k < 24; k++) a += W[j * 24 + k] * h[k];
        if (isbf16) ((__hip_bfloat16*)out)[s * 2 + j] = __float2bfloat16(a);
        else        ((float*)out)[s * 2 + j] = a;
    }
}

extern "C" void kernel_launch(void* const* d_in, const int* in_sizes, int n_in,
                              void* d_out, int out_size, void* d_ws, size_t ws_size,
                              hipStream_t stream)
{
    // ---- workspace layout ----
    int*   ip    = (int*)d_ws;        // ip[0]: dtype flag; ip[256 + l*64]: progress[l]
    int*   flag  = ip;
    int*   prog  = ip + 256;
    float* ws    = (float*)d_ws;
    float* conv0 = ws + 1024;

    IngestArgs ia;
    float* conv[N_IN];
    {
        float* p = conv0;
        for (int i = 0; i < N_IN; i++) {
            conv[i] = p;
            ia.src[i] = d_in[i];
            ia.dst[i] = p;
            ia.n[i]   = in_sizes[i];
            p += in_sizes[i];
        }
    }
    float* h2   = conv0 + 191000;       // [S,20]  327,680
    float* seq0 = h2 + 327680;          // 5 x [S,48]
    float* seq1 = seq0 + 786432;
    float* seq2 = seq1 + 786432;
    float* seq3 = seq2 + 786432;
    float* seq4 = seq3 + 786432;
    float* rnnA = seq4 + 786432;        // [S,24]
    float* rnnB = rnnA + 393216;        // [S,24]

    const int TPB = 256;
    const int NB  = S_LEN / TPB;  // 64

    detect_kernel<<<1, 64, 0, stream>>>(d_in[1], in_sizes[1], flag);
    ingest_kernel<<<128, 256, 0, stream>>>(ia, flag);
    init_kernel<<<1, 512, 0, stream>>>(prog);

    fc12_kernel<<<NB, TPB, 0, stream>>>(conv[0], conv[1], conv[2], conv[3], conv[4], h2);

    PipeArgs pa;
    pa.h2 = h2;
    pa.l0_Wih = conv[5];  pa.l0_Whh = conv[6];  pa.l0_bih = conv[7];  pa.l0_bhh = conv[8];
    pa.lr_Wih = conv[9];  pa.lr_Whh = conv[10]; pa.lr_bih = conv[11]; pa.lr_bhh = conv[12];
    pa.r0_Wih = conv[13]; pa.r0_Whh = conv[14]; pa.r0_bih = conv[15]; pa.r0_bhh = conv[16];
    pa.r1_Wih = conv[17]; pa.r1_Whh = conv[18]; pa.r1_bih = conv[19]; pa.r1_bhh = conv[20];
    pa.seq0 = seq0; pa.seq1 = seq1; pa.seq2 = seq2; pa.seq3 = seq3; pa.seq4 = seq4;
    pa.rnnA = rnnA; pa.rnnB = rnnB;
    pa.prog = prog;

    pipeline_kernel<<<7, 192, 0, stream>>>(pa);

    out_kernel<<<NB, TPB, 0, stream>>>(rnnB, conv[21], conv[22], d_out, flag);
}

// Round 6
// 11097.457 us; speedup vs baseline: 1.0293x; 1.0293x over previous
//
#include <hip/hip_runtime.h>
#include <hip/hip_bf16.h>

#define S_LEN 16384
#define N_IN 23
#define CH2 32
#define NCH2 (S_LEN / CH2)     // 512 chunks
#define RING_D 8               // ring slots per stage

// ---------------- fast activations (v_exp_f32 + v_rcp_f32) ----------------
__device__ __forceinline__ float fsig(float x) {
    return __builtin_amdgcn_rcpf(1.f + __expf(-x));   // exp(+inf)->inf, rcp(inf)->0: safe
}
__device__ __forceinline__ float ftanh_fast(float x) {
    float e = __expf(-2.f * fabsf(x));                // in (0,1]
    float r = (1.f - e) * __builtin_amdgcn_rcpf(1.f + e);
    return x >= 0.f ? r : -r;
}
// broadcast lane k's value of v to all lanes (VALU, no LDS)
__device__ __forceinline__ float rlane(float v, int k) {
    return __uint_as_float(__builtin_amdgcn_readlane(__float_as_uint(v), k));
}

// ---------------- dtype autodetect (bf16 vs fp32 input buffers) ----------------
__global__ void detect_kernel(const void* probe, int nsamp, int* flag)
{
    if (blockIdx.x == 0 && threadIdx.x == 0) {
        const unsigned short* p = (const unsigned short*)probe;
        int isbf16 = 1;
        for (int i = 0; i < nsamp; i++) {
            float v = __uint_as_float(((unsigned int)p[i]) << 16);
            if (!(fabsf(v) < 1e4f)) { isbf16 = 0; break; }
        }
        *flag = isbf16;
    }
}

// ---------------- ingest: convert all inputs to fp32 in ws ----------------
struct IngestArgs {
    const void* src[N_IN];
    float*      dst[N_IN];
    int         n[N_IN];
};

__global__ void ingest_kernel(IngestArgs args, const int* __restrict__ flag)
{
    const int isbf16 = *flag;
    const int tid    = blockIdx.x * blockDim.x + threadIdx.x;
    const int stride = gridDim.x * blockDim.x;
    for (int i = 0; i < N_IN; i++) {
        const int n = args.n[i];
        float* dst  = args.dst[i];
        if (isbf16) {
            const unsigned short* s = (const unsigned short*)args.src[i];
            for (int j = tid; j < n; j += stride)
                dst[j] = __uint_as_float(((unsigned int)s[j]) << 16);
        } else {
            const float* s = (const float*)args.src[i];
            for (int j = tid; j < n; j += stride)
                dst[j] = s[j];
        }
    }
}

// ---------------- zero the progress flags (ws is poisoned each launch) --------
__global__ void init_kernel(int* prog)
{
    int t = threadIdx.x;
    if (t < 1024) prog[t] = 0;
}

// ---------------- fc1 + fc2 (parallel) ----------------
__global__ void fc12_kernel(const float* __restrict__ x,
                            const float* __restrict__ W1, const float* __restrict__ b1,
                            const float* __restrict__ W2, const float* __restrict__ b2,
                            float* __restrict__ h2out)
{
    int s = blockIdx.x * blockDim.x + threadIdx.x;
    if (s >= S_LEN) return;
    float xin[6];
#pragma unroll
    for (int k = 0; k < 6; k++) xin[k] = x[s * 6 + k];
    float h1[20];
#pragma unroll
    for (int j = 0; j < 20; j++) {
        float a = b1[j];
#pragma unroll
        for (int k = 0; k < 6; k++) a += W1[j * 6 + k] * xin[k];
        h1[j] = a > 0.f ? a : 0.f;
    }
#pragma unroll
    for (int j = 0; j < 20; j++) {
        float a = b2[j];
#pragma unroll
        for (int k = 0; k < 20; k++) a += W2[j * 20 + k] * h1[k];
        h2out[s * 20 + j] = a > 0.f ? a : 0.f;
    }
}

// =========== producer: xw[s,g] = bih[g]+bhh[g] + Wih[g,:].in[s,:], chunked ====
// Register-tiled GEMM, 256 threads: thread = (row-group rg of 3 gates) x (sl group).
// Ring-buffered output with back-pressure from the consumer scan block.
template <int DIN, int NG>
__device__ void producer_block(const float* __restrict__ in,    // [S, DIN]
                               const float* __restrict__ Wih,   // [NG, DIN]
                               const float* __restrict__ bih,
                               const float* __restrict__ bhh,
                               float* __restrict__ ring,        // [RING_D][CH2*NG]
                               int* my_prog, int* in_prog, int* cons_prog,
                               float* smem)
{
    constexpr int GR  = NG / 3;      // row groups
    constexpr int GS  = 256 / GR;    // sl groups
    constexpr int SLT = CH2 / GS;    // sl per thread

    const int t  = threadIdx.x;
    const int rg = t % GR;
    const int sg = t / GR;

    float* in_sh = smem;             // CH2*DIN
    float* xw_sh = smem + CH2 * DIN; // CH2*NG

    float w[3][DIN];
    float bs[3];
#pragma unroll
    for (int r = 0; r < 3; r++) {
        const int row = rg * 3 + r;
#pragma unroll
        for (int k = 0; k < DIN; k++) w[r][k] = Wih[row * DIN + k];
        bs[r] = bih[row] + bhh[row];
    }

    const float4* x4 = (const float4*)in_sh;

    for (int c = 0; c < NCH2; c++) {
        if (t == 0) {
            if (in_prog) {
                while (__hip_atomic_load(in_prog, __ATOMIC_ACQUIRE, __HIP_MEMORY_SCOPE_AGENT) < c + 1)
                    __builtin_amdgcn_s_sleep(1);
            }
            if (c >= RING_D) {  // don't overwrite a slot the consumer hasn't used
                while (__hip_atomic_load(cons_prog, __ATOMIC_ACQUIRE, __HIP_MEMORY_SCOPE_AGENT) < c - RING_D + 1)
                    __builtin_amdgcn_s_sleep(1);
            }
        }
        __syncthreads();
        {   // input chunk -> LDS
            const float4* gsrc = (const float4*)(in + (size_t)c * CH2 * DIN);
            float4* ldst = (float4*)in_sh;
            for (int i = t; i < CH2 * DIN / 4; i += 256) ldst[i] = gsrc[i];
        }
        __syncthreads();

#pragma unroll
        for (int i = 0; i < SLT; i++) {
            const int sl = sg * SLT + i;
            float a0 = bs[0], a1 = bs[1], a2 = bs[2];
#pragma unroll
            for (int k = 0; k < DIN / 4; k++) {
                float4 xv = x4[sl * (DIN / 4) + k];
                a0 += w[0][4 * k + 0] * xv.x; a0 += w[0][4 * k + 1] * xv.y;
                a0 += w[0][4 * k + 2] * xv.z; a0 += w[0][4 * k + 3] * xv.w;
                a1 += w[1][4 * k + 0] * xv.x; a1 += w[1][4 * k + 1] * xv.y;
                a1 += w[1][4 * k + 2] * xv.z; a1 += w[1][4 * k + 3] * xv.w;
                a2 += w[2][4 * k + 0] * xv.x; a2 += w[2][4 * k + 1] * xv.y;
                a2 += w[2][4 * k + 2] * xv.z; a2 += w[2][4 * k + 3] * xv.w;
            }
            xw_sh[sl * NG + rg * 3 + 0] = a0;
            xw_sh[sl * NG + rg * 3 + 1] = a1;
            xw_sh[sl * NG + rg * 3 + 2] = a2;
        }
        __syncthreads();
        {   // xw chunk -> ring slot
            const float4* lsrc = (const float4*)xw_sh;
            float4* gdst = (float4*)(ring + (size_t)(c % RING_D) * CH2 * NG);
            for (int i = t; i < CH2 * NG / 4; i += 256) gdst[i] = lsrc[i];
        }
        __syncthreads();   // drain vmcnt before publishing
        if (t == 0)
            __hip_atomic_store(my_prog, c + 1, __ATOMIC_RELEASE, __HIP_MEMORY_SCOPE_AGENT);
    }
}

// =========== LSTM scan: 192 gate threads, readlane h-broadcast ================
// Per step: 48 readlane + 48 fma + act -> gate (LDS b32) -> barrier ->
// each wave redundantly updates all 48 cells (h stays in lane registers).
__device__ void lstm_scan(const float* __restrict__ Whh,     // [192, 48]
                          const float* __restrict__ ring,    // xw ring [RING_D][CH2*192]
                          float* __restrict__ hseq,          // [S, 48]
                          int* my_prog, int* prod_prog, float* smem)
{
    const int t    = threadIdx.x;    // 0..255 (t>=192: barrier/copy helper)
    const int wv   = t >> 6;
    const int lane = t & 63;
    const bool active = (t < 192);

    float* xw_sh  = smem;                       // CH2*192 = 6144
    float* h_hist = xw_sh + CH2 * 192;          // CH2*48  = 1536
    float* gates2 = h_hist + CH2 * 48;          // 2*192

    float whh[48];
    if (active) {
#pragma unroll
        for (int k = 0; k < 48; k++) whh[k] = Whh[t * 48 + k];
    }
    const bool tanh_gate = (t >= 96 && t < 144);
    float hvec  = 0.f;   // lanes 0..47 of each active wave: h_j
    float ccell = 0.f;   // redundant per-wave cell state

    for (int c = 0; c < NCH2; c++) {
        if (t == 0) {
            while (__hip_atomic_load(prod_prog, __ATOMIC_ACQUIRE, __HIP_MEMORY_SCOPE_AGENT) < c + 1)
                __builtin_amdgcn_s_sleep(1);
        }
        __syncthreads();
        {   // ring slot -> LDS
            const float4* gsrc = (const float4*)(ring + (size_t)(c % RING_D) * CH2 * 192);
            float4* ldst = (float4*)xw_sh;
            for (int i = t; i < CH2 * 192 / 4; i += 256) ldst[i] = gsrc[i];
        }
        __syncthreads();

        float xwv = active ? xw_sh[t] : 0.f;

        for (int sl = 0; sl < CH2; sl++) {
            float* g = gates2 + (sl & 1) * 192;
            if (active) {
                float a0 = xwv, a1 = 0.f, a2 = 0.f, a3 = 0.f;
#pragma unroll
                for (int k = 0; k < 48; k += 4) {
                    a0 += rlane(hvec, k + 0) * whh[k + 0];
                    a1 += rlane(hvec, k + 1) * whh[k + 1];
                    a2 += rlane(hvec, k + 2) * whh[k + 2];
                    a3 += rlane(hvec, k + 3) * whh[k + 3];
                }
                float a = (a0 + a1) + (a2 + a3);
                // i,f,o: sigmoid; g: tanh(a)=2*sigmoid(2a)-1 (NaN-safe)
                g[t] = tanh_gate ? (2.f * fsig(2.f * a) - 1.f) : fsig(a);
            }
            __syncthreads();   // the only barrier in the step
            if (active) {
                if (lane < 48) {
                    float iv = g[lane], fv = g[lane + 48], gv = g[lane + 96], ov = g[lane + 144];
                    ccell = fv * ccell + iv * gv;
                    float h = ov * ftanh_fast(ccell);
                    hvec = h;                              // stays in registers
                    if (wv == 0) h_hist[sl * 48 + lane] = h;
                }
                xwv = xw_sh[((sl + 1 < CH2) ? sl + 1 : 0) * 192 + t];  // prefetch
            }
            // next step writes the other gates parity buffer -> no WAR race
        }
        __syncthreads();
        {   // h chunk -> global
            const float4* lsrc = (const float4*)h_hist;
            float4* gdst = (float4*)(hseq + (size_t)c * CH2 * 48);
            for (int i = t; i < CH2 * 48 / 4; i += 256) gdst[i] = lsrc[i];
        }
        __syncthreads();   // drain vmcnt before publishing
        if (t == 0)
            __hip_atomic_store(my_prog, c + 1, __ATOMIC_RELEASE, __HIP_MEMORY_SCOPE_AGENT);
    }
}

// =========== tanh-RNN scan: single wave, barrier-free step loop ===============
__device__ void rnn_scan(const float* __restrict__ Whh,      // [24, 24]
                         const float* __restrict__ ring,     // xw ring [RING_D][CH2*24]
                         float* __restrict__ hseq,           // [S, 24]
                         int* my_prog, int* prod_prog, float* smem)
{
    const int t = threadIdx.x;
    float* xw_sh  = smem;                 // CH2*24 = 768
    float* h_hist = xw_sh + CH2 * 24;     // CH2*24 = 768

    float whh[24];
    if (t < 24) {
#pragma unroll
        for (int k = 0; k < 24; k++) whh[k] = Whh[t * 24 + k];
    }
    float hvec = 0.f;   // lanes 0..23: h_j

    for (int c = 0; c < NCH2; c++) {
        if (t == 0) {
            while (__hip_atomic_load(prod_prog, __ATOMIC_ACQUIRE, __HIP_MEMORY_SCOPE_AGENT) < c + 1)
                __builtin_amdgcn_s_sleep(1);
        }
        __syncthreads();
        {
            const float4* gsrc = (const float4*)(ring + (size_t)(c % RING_D) * CH2 * 24);
            float4* ldst = (float4*)xw_sh;
            for (int i = t; i < CH2 * 24 / 4; i += 256) ldst[i] = gsrc[i];
        }
        __syncthreads();

        if (t < 64) {   // one wave runs the whole recurrence in lockstep
            float xwv = (t < 24) ? xw_sh[t] : 0.f;
            for (int sl = 0; sl < CH2; sl++) {
                float a0 = xwv, a1 = 0.f, a2 = 0.f, a3 = 0.f;
#pragma unroll
                for (int k = 0; k < 24; k += 4) {
                    a0 += rlane(hvec, k + 0) * whh[k + 0];
                    a1 += rlane(hvec, k + 1) * whh[k + 1];
                    a2 += rlane(hvec, k + 2) * whh[k + 2];
                    a3 += rlane(hvec, k + 3) * whh[k + 3];
                }
                float h = ftanh_fast((a0 + a1) + (a2 + a3));
                if (t < 24) {
                    hvec = h;                      // wave-lockstep, no barrier
                    h_hist[sl * 24 + t] = h;
                    xwv = xw_sh[((sl + 1 < CH2) ? sl + 1 : 0) * 24 + t];
                }
            }
        }
        __syncthreads();
        {
            const float4* lsrc = (const float4*)h_hist;
            float4* gdst = (float4*)(hseq + (size_t)c * CH2 * 24);
            for (int i = t; i < CH2 * 24 / 4; i += 256) gdst[i] = lsrc[i];
        }
        __syncthreads();
        if (t == 0)
            __hip_atomic_store(my_prog, c + 1, __ATOMIC_RELEASE, __HIP_MEMORY_SCOPE_AGENT);
    }
}

// ---------------- the 14-block pipeline megakernel ----------------
struct PipeArgs {
    const float* h2;
    const float* l0_Wih; const float* l0_Whh; const float* l0_bih; const float* l0_bhh;
    const float* lr_Wih; const float* lr_Whh; const float* lr_bih; const float* lr_bhh;
    const float* r0_Wih; const float* r0_Whh; const float* r0_bih; const float* r0_bhh;
    const float* r1_Wih; const float* r1_Whh; const float* r1_bih; const float* r1_bhh;
    float* seq0; float* seq1; float* seq2; float* seq3; float* seq4;
    float* rnnA; float* rnnB;
    float* ring[7];   // xw rings per stage
    int* prog;        // scan l: prog[l*64]; producer l: prog[(8+l)*64]
};

__global__ void __launch_bounds__(256, 1) pipeline_kernel(PipeArgs a)
{
    __shared__ float smem[8064];    // max(scan 8064, producer 7680) floats
    const int b = blockIdx.x;
    const float* seqin[7] = {a.h2, a.seq0, a.seq1, a.seq2, a.seq3, a.seq4, a.rnnA};
    float* seqout[7] = {a.seq0, a.seq1, a.seq2, a.seq3, a.seq4, a.rnnA, a.rnnB};
    int* sp[7]; int* pp[7];
    for (int l = 0; l < 7; l++) { sp[l] = a.prog + l * 64; pp[l] = a.prog + (8 + l) * 64; }

    if (b < 7) {
        // ---- producers ----
        const int l = b;
        int* inp = (l == 0) ? nullptr : sp[l - 1];
        if (l == 0) {
            producer_block<20, 192>(a.h2, a.l0_Wih, a.l0_bih, a.l0_bhh,
                                    a.ring[0], pp[0], inp, sp[0], smem);
        } else if (l <= 4) {
            producer_block<48, 192>(seqin[l],
                                    a.lr_Wih + (size_t)(l - 1) * 192 * 48,
                                    a.lr_bih + (size_t)(l - 1) * 192,
                                    a.lr_bhh + (size_t)(l - 1) * 192,
                                    a.ring[l], pp[l], inp, sp[l], smem);
        } else if (l == 5) {
            producer_block<48, 24>(a.seq4, a.r0_Wih, a.r0_bih, a.r0_bhh,
                                   a.ring[5], pp[5], inp, sp[5], smem);
        } else {
            producer_block<24, 24>(a.rnnA, a.r1_Wih, a.r1_bih, a.r1_bhh,
                                   a.ring[6], pp[6], inp, sp[6], smem);
        }
    } else {
        // ---- scans ----
        const int l = b - 7;
        if (l == 0) {
            lstm_scan(a.l0_Whh, a.ring[0], seqout[0], sp[0], pp[0], smem);
        } else if (l <= 4) {
            lstm_scan(a.lr_Whh + (size_t)(l - 1) * 192 * 48,
                      a.ring[l], seqout[l], sp[l], pp[l], smem);
        } else if (l == 5) {
            rnn_scan(a.r0_Whh, a.ring[5], seqout[5], sp[5], pp[5], smem);
        } else {
            rnn_scan(a.r1_Whh, a.ring[6], seqout[6], sp[6], pp[6], smem);
        }
    }
}

// ---------------- epilogue: relu + fc4, bf16 or fp32 out per flag ----------------
__global__ void out_kernel(const float* __restrict__ hin,
                           const float* __restrict__ W,  // [2, 24]
                           const float* __restrict__ b,  // [2]
                           void* __restrict__ out,
                           const int* __restrict__ flag)
{
    int s = blockIdx.x * blockDim.x + threadIdx.x;
    if (s >= S_LEN) return;
    const int isbf16 = *flag;
    float h[24];
#pragma unroll
    for (int k = 0; k < 24; k++) {
        float v = hin[s * 24 + k];
        h[k] = v > 0.f ? v : 0.f;
    }
#pragma unroll
    for (int j = 0; j < 2; j++) {
        float a = b[j];
#pragma unroll
        for (int k = 0; k < 24; k++) a += W[j * 24 + k] * h[k];
        if (isbf16) ((__hip_bfloat16*)out)[s * 2 + j] = __float2bfloat16(a);
        else        ((float*)out)[s * 2 + j] = a;
    }
}

extern "C" void kernel_launch(void* const* d_in, const int* in_sizes, int n_in,
                              void* d_out, int out_size, void* d_ws, size_t ws_size,
                              hipStream_t stream)
{
    // ---- workspace layout (floats from ws base) ----
    int*   ip    = (int*)d_ws;        // [0]: dtype flag; [256..1280): progress slots
    int*   flag  = ip;
    int*   prog  = ip + 256;
    float* ws    = (float*)d_ws;
    float* conv0 = ws + 4096;

    IngestArgs ia;
    float* conv[N_IN];
    {
        float* p = conv0;
        for (int i = 0; i < N_IN; i++) {
            conv[i] = p;
            ia.src[i] = d_in[i];
            ia.dst[i] = p;
            ia.n[i]   = in_sizes[i];
            p += in_sizes[i];
        }
    }
    float* h2   = conv0 + 191000;       // [S,20]  327,680
    float* seq0 = h2 + 327680;          // 5 x [S,48]
    float* seq1 = seq0 + 786432;
    float* seq2 = seq1 + 786432;
    float* seq3 = seq2 + 786432;
    float* seq4 = seq3 + 786432;
    float* rnnA = seq4 + 786432;        // [S,24]
    float* rnnB = rnnA + 393216;        // [S,24]
    float* rbase = rnnB + 393216;       // rings
    float* ring[7];
    {
        float* p = rbase;
        for (int l = 0; l < 5; l++) { ring[l] = p; p += RING_D * CH2 * 192; }  // 49,152 ea
        for (int l = 5; l < 7; l++) { ring[l] = p; p += RING_D * CH2 * 24;  }  // 6,144 ea
    }

    const int TPB = 256;
    const int NB  = S_LEN / TPB;  // 64

    detect_kernel<<<1, 64, 0, stream>>>(d_in[1], in_sizes[1], flag);
    ingest_kernel<<<128, 256, 0, stream>>>(ia, flag);
    init_kernel<<<1, 1024, 0, stream>>>(prog);

    fc12_kernel<<<NB, TPB, 0, stream>>>(conv[0], conv[1], conv[2], conv[3], conv[4], h2);

    PipeArgs pa;
    pa.h2 = h2;
    pa.l0_Wih = conv[5];  pa.l0_Whh = conv[6];  pa.l0_bih = conv[7];  pa.l0_bhh = conv[8];
    pa.lr_Wih = conv[9];  pa.lr_Whh = conv[10]; pa.lr_bih = conv[11]; pa.lr_bhh = conv[12];
    pa.r0_Wih = conv[13]; pa.r0_Whh = conv[14]; pa.r0_bih = conv[15]; pa.r0_bhh = conv[16];
    pa.r1_Wih = conv[17]; pa.r1_Whh = conv[18]; pa.r1_bih = conv[19]; pa.r1_bhh = conv[20];
    pa.seq0 = seq0; pa.seq1 = seq1; pa.seq2 = seq2; pa.seq3 = seq3; pa.seq4 = seq4;
    pa.rnnA = rnnA; pa.rnnB = rnnB;
    for (int l = 0; l < 7; l++) pa.ring[l] = ring[l];
    pa.prog = prog;

    pipeline_kernel<<<14, 256, 0, stream>>>(pa);

    out_kernel<<<NB, TPB, 0, stream>>>(rnnB, conv[21], conv[22], d_out, flag);
}